// Round 12
// baseline (93.268 us; speedup 1.0000x reference)
//
#include <hip/hip_runtime.h>

// FlowNetC correlation, B=16 C=256 H=48 W=64, 21x21 displacements (stride 2, +/-20).
// out[b, i*21+j, h, w] = sum_c in1[b,c,h,w] * in2[b,c,h+2i-20,w+2j-20]  (zero OOB)
//
// v12 = v11 + cross-oy DMA pipeline (m201-style raw barriers + counted vmcnt).
// v11 was LDS/overlap-bound: single-buffered plane + __syncthreads (vmcnt(0)
// drain) serialized DMA-wait -> compute -> copyout per oy. Now:
//  - bplane[2 buf][2 par][4096w]: while computing oy from buf, oy+1's 8 glds16
//    stream into buf^1 and stay IN FLIGHT across the barriers (raw s_barrier,
//    no vmcnt drain); s_waitcnt vmcnt(8) waits exactly for oy's loads (in-order
//    retirement; just-issued 8 remain outstanding). Tail: vmcnt(0).
//  - oy split in 2 chunks -> grid 1536 = 3 exact rounds at 2 blocks/CU
//    (LDS 71.2KB), fixing the 1.5-round imbalance.
// Clamped lanes (w2p OOB) read a dummy row (broadcast, values masked at consume)
// -> per-wave vmcnt suffices for real data (each wave stages the rows it reads).

#define NB 16
#define NC 256
#define NH 48
#define NW 64
#define HW (NH * NW)
#define CHW (NC * NH * NW)
#define ND 21
#define NDISP (ND * ND)

typedef __fp16 half2v __attribute__((ext_vector_type(2)));
typedef _Float16 f16x8 __attribute__((ext_vector_type(8)));
typedef float f32x16 __attribute__((ext_vector_type(16)));

__device__ __forceinline__ unsigned pk2(float lo, float hi) {
    half2v h = __builtin_amdgcn_cvt_pkrtz(lo, hi);
    return __builtin_bit_cast(unsigned, h);
}
__device__ __forceinline__ half2v uph(unsigned u) {
    return __builtin_bit_cast(half2v, u);
}

__device__ __forceinline__ void glds16(unsigned* l, const unsigned* g) {
    __builtin_amdgcn_global_load_lds(
        (const __attribute__((address_space(1))) unsigned*)g,
        (__attribute__((address_space(3))) unsigned*)l, 16, 0, 0);
}

// ---------------- Kernel T: transpose + pack (LDS-staged) ----------------
// src [b][c 256][h][w 64] f32 -> dst [(b_local*48+h)*2+par][w' 32][c2 128] u32
__global__ __launch_bounds__(256, 4)
void transpose_pack(const float* __restrict__ in1,
                    const float* __restrict__ in2,
                    unsigned* __restrict__ t1,
                    unsigned* __restrict__ t2,
                    int b_base, int nwg48) {
    __shared__ unsigned xs[64 * 129];        // [w 64][c2 128 +1 pad] -> conflict-free
    const int bx = blockIdx.x;
    const int which = (bx >= nwg48) ? 1 : 0;
    const int r = bx - which * nwg48;
    const int b_local = r / NH;
    const int h = r % NH;
    const float* src = (which ? in2 : in1) + (size_t)(b_base + b_local) * CHW + (size_t)h * NW;
    unsigned* dst = (which ? t2 : t1) + (size_t)((b_local * NH + h) * 2) * 4096;

    const int t = threadIdx.x;
    const int w = t & 63;
    const int c2b = t >> 6;                  // 0..3

    #pragma unroll 8
    for (int it = 0; it < 32; ++it) {
        const int c2 = c2b * 32 + it;
        const float lo = src[(size_t)(2 * c2) * HW + w];
        const float hi = src[(size_t)(2 * c2 + 1) * HW + w];
        xs[w * 129 + c2] = pk2(lo, hi);
    }
    __syncthreads();
    #pragma unroll 8
    for (int it = 0; it < 32; ++it) {
        const int k = t + 256 * it;          // 0..8191
        const int c2 = k & 127;
        const int wp = k >> 7;               // par = wp>>5, w' = wp&31
        dst[(size_t)(wp >> 5) * 4096 + (size_t)(wp & 31) * 128 + c2] =
            xs[(2 * (wp & 31) + (wp >> 5)) * 129 + c2];
    }
}

// ---------------- Kernel 2: banded-Gram MFMA, pipelined DMA-staged B ----------------
__global__ __launch_bounds__(256, 2)
void corr_mfma(const unsigned* __restrict__ in1T, const unsigned* __restrict__ in2T,
               float* __restrict__ out, int b_base, int nbh) {
    __shared__ __align__(16) unsigned bplane[2][2][4096];  // [buf][par][32 rows x 128 w]
    __shared__ float slab[1428];                           // [par 2][j 21][34]

    const int t = threadIdx.x;
    const int lane = t & 63;
    const int wid = t >> 6;
    const int par = wid >> 1;
    const int nt = wid & 1;
    const int ln31 = lane & 31;
    const int kh = lane >> 5;

    const int bx = blockIdx.x;
    const int c0 = (bx & 1) * 11;           // oy chunk: [0,10] / [11,20]
    const int r = bx >> 1;
    const int cpx = nbh >> 3;               // nbh = bc*48, divisible by 8
    const int L = (r & 7) * cpx + (r >> 3);
    const int b_local = L / NH;
    const int h = L % NH;
    const int b = b_base + b_local;

    float* out_b = out + (size_t)b * NDISP * HW + (size_t)h * NW;

    // B-lane geometry: w2' = nt*32 - 16 + ln31, zero OOB (masked at consume)
    const int w2p = nt * 32 - 16 + ln31;
    const bool bval = ((unsigned)w2p < 32u);
    const int w2c = bval ? w2p : 0;

    const int lo0 = (h >= 20) ? 0 : ((21 - h) >> 1);
    const int hi0 = min(20, (67 - h) >> 1);
    const int ce = min(c0 + 10, ND - 1);

    // zero slabs for OOB oy rows within this chunk
    #pragma unroll 1
    for (int oy = c0; oy <= ce; ++oy) {
        if (oy >= lo0 && oy <= hi0) continue;
        #pragma unroll
        for (int s_ = 0; s_ < 6; ++s_) {
            int k_ = t + 256 * s_;
            if (k_ < ND * NW)
                out_b[(size_t)(oy * ND + (k_ >> 6)) * HW + (k_ & 63)] = 0.f;
        }
    }

    const int s = max(c0, lo0), e = min(ce, hi0);
    if (s > e) return;

    // ---- A-frags to registers (once per block) ----
    const unsigned* pa = in1T +
        ((size_t)((b_local * NH + h) * 2 + par)) * 4096 + (size_t)ln31 * 128 + kh * 4;
    uint4 av[16];
    #pragma unroll
    for (int kk = 0; kk < 16; ++kk) av[kk] = *(const uint4*)(pa + 8 * kk);

    const unsigned* gplanes = in2T + ((size_t)(b_local * NH) * 2) * 4096;
    const int rsw = w2c & 7;

#define STAGE(oy_, buf_)                                                      \
    do {                                                                      \
        const unsigned* gp = gplanes +                                        \
            ((size_t)((h + 2 * (oy_) - 20) * 2 + par)) * 4096;                \
        unsigned* lp = &bplane[buf_][par][0];                                 \
        _Pragma("unroll") for (int il = 0; il < 8; ++il) {                    \
            const int ip = (nt << 3) + il;                                    \
            const int row = (ip << 1) + kh;                                   \
            glds16(lp + (ip << 8),                                            \
                   gp + row * 128 + ((ln31 ^ (row & 7)) << 2));               \
        }                                                                     \
    } while (0)

#define SCAT(acc_)                                                            \
    do {                                                                      \
        _Pragma("unroll") for (int r_ = 0; r_ < 16; ++r_) {                   \
            const int m_ = (r_ & 3) + 8 * (r_ >> 2) + 4 * kh;                 \
            const int j_ = 32 * nt + ln31 - m_ - 6;                           \
            if ((unsigned)j_ < (unsigned)ND)                                  \
                slab[par * 714 + j_ * 34 + m_] = acc_[r_];                    \
        }                                                                     \
    } while (0)

#define COPYOUT(oy_)                                                          \
    do {                                                                      \
        _Pragma("unroll") for (int s_ = 0; s_ < 6; ++s_) {                    \
            int k_ = t + 256 * s_;                                            \
            if (k_ < ND * NW) {                                               \
                int j_ = k_ >> 6, w_ = k_ & 63;                               \
                out_b[(size_t)((oy_)*ND + j_) * HW + w_] =                    \
                    slab[(w_ & 1) * 714 + j_ * 34 + (w_ >> 1)];               \
            }                                                                 \
        }                                                                     \
    } while (0)

    // prologue: DMA oy=s into buf 0
    STAGE(s, 0);

    int buf = 0;
    #pragma unroll 1
    for (int oy = s; oy <= e; ++oy, buf ^= 1) {
        // phase-top barrier: all waves done reading bplane[buf^1] (prev phase)
        asm volatile("s_waitcnt lgkmcnt(0)" ::: "memory");
        __builtin_amdgcn_s_barrier();
        __builtin_amdgcn_sched_barrier(0);

        if (oy + 1 <= e) {
            STAGE(oy + 1, buf ^ 1);           // in flight across this whole phase
            asm volatile("s_waitcnt vmcnt(8)" ::: "memory");  // oy's 8 done (in-order)
        } else {
            asm volatile("s_waitcnt vmcnt(0)" ::: "memory");
        }
        __builtin_amdgcn_sched_barrier(0);

        // ---- compute from bplane[buf] ----
        const unsigned* lrow = &bplane[buf][par][0] + w2c * 128;
        f32x16 acc;
        #pragma unroll
        for (int i = 0; i < 16; ++i) acc[i] = 0.f;

        __builtin_amdgcn_s_setprio(1);
        #pragma unroll
        for (int kk = 0; kk < 16; ++kk) {
            const uint4 qv = *(const uint4*)(lrow + (((2 * kk + kh) ^ rsw) << 2));
            uint4 qq;
            qq.x = bval ? qv.x : 0u;
            qq.y = bval ? qv.y : 0u;
            qq.z = bval ? qv.z : 0u;
            qq.w = bval ? qv.w : 0u;
            acc = __builtin_amdgcn_mfma_f32_32x32x16_f16(
                __builtin_bit_cast(f16x8, av[kk]),
                __builtin_bit_cast(f16x8, qq), acc, 0, 0, 0);
        }
        __builtin_amdgcn_s_setprio(0);

        SCAT(acc);
        asm volatile("s_waitcnt lgkmcnt(0)" ::: "memory");  // scat visible
        __builtin_amdgcn_s_barrier();
        __builtin_amdgcn_sched_barrier(0);
        COPYOUT(oy);
        // copyout stores drain under the NEXT phase's vmcnt(8) (older than the
        // in-flight stage loads? no: older stores retire first -- harmless).
    }
#undef STAGE
#undef SCAT
#undef COPYOUT
}

// ---------------- Fallback: v3 dot2 kernel ----------------
#define NCB 16
#define IN1_P 36
#define IN1_C2 (2 * IN1_P)
#define IN1_WORDS (128 * IN1_C2)
#define IN2_P 52
#define IN2_C2 (2 * IN2_P)
#define IN2_WAVE (8 * IN2_C2)
#define LDS_WORDS (IN1_WORDS + 4 * IN2_WAVE)

#if defined(__has_builtin)
#if __has_builtin(__builtin_amdgcn_fdot2)
#define HAVE_FDOT2 1
#endif
#endif
__device__ __forceinline__ float fdot2f(half2v a, half2v b, float c) {
#ifdef HAVE_FDOT2
    return __builtin_amdgcn_fdot2(a, b, c, false);
#else
    return c + (float)a.x * (float)b.x + (float)a.y * (float)b.y;
#endif
}
#define WW(u, m) uph(((m) & 1) ? wn[u][(m) >> 1].y : wn[u][(m) >> 1].x)

__global__ __launch_bounds__(256, 3)
void corr_kernel(const float* __restrict__ in1, const float* __restrict__ in2,
                 float* __restrict__ out) {
    __shared__ __align__(16) unsigned lds[LDS_WORDS];
    unsigned* in1_s = lds;
    const int t = threadIdx.x;
    const int lane = t & 63;
    const int wid = t >> 6;
    const int tw = lane & 7;
    const int oh = (lane >> 3) & 1;
    const int p = (lane >> 4) & 1;
    const int chalf = (lane >> 5) & 1;
    unsigned* in2w = lds + IN1_WORDS + wid * IN2_WAVE;
    const int bx = blockIdx.x;
    const int L = (bx & 7) * 96 + (bx >> 3);
    const int b = L / NH;
    const int h = L % NH;
    const float* in1_row = in1 + (size_t)b * CHW + (size_t)h * NW;
    for (int i = lane; i < IN2_WAVE; i += 64) in2w[i] = 0u;
    #pragma unroll 1
    for (int j = 0; j < 8; ++j) {
        const int task = t + 256 * j;
        const int c2 = task >> 4;
        const int c4 = task & 15;
        const float4 u0 = ((const float4*)(in1_row + (size_t)(2 * c2) * HW))[c4];
        const float4 u1 = ((const float4*)(in1_row + (size_t)(2 * c2 + 1) * HW))[c4];
        unsigned* d0 = &in1_s[c2 * IN1_C2 + 2 * c4];
        *(uint2*)&d0[0] = make_uint2(pk2(u0.x, u1.x), pk2(u0.z, u1.z));
        *(uint2*)&d0[IN1_P] = make_uint2(pk2(u0.y, u1.y), pk2(u0.w, u1.w));
    }
    __syncthreads();
    const int q = lane >> 4;
    const int col4 = lane & 15;
    const int lo = (h >= 20) ? 0 : ((21 - h) >> 1);
    const int hi = min(20, (67 - h) >> 1);
    const int nv = hi - lo + 1;
    const int rot = (wid + h) & 3;
    #pragma unroll 1
    for (int oy = rot; oy < ND; oy += 4) {
        if (oy >= lo && oy <= hi) continue;
        float* orow = out + ((size_t)(b * NDISP + oy * ND) * NH + h) * NW;
        #pragma unroll
        for (int o = 0; o < ND; ++o) orow[(size_t)o * HW + lane] = 0.f;
    }
    #pragma unroll 1
    for (int k = rot; k < nv; k += 4) {
        const int oyi = lo + k;
        const int row = h + 2 * oyi - 20;
        float* orow = out + ((size_t)(b * NDISP + oyi * ND) * NH + h) * NW;
        const float* in2_row = in2 + (size_t)b * CHW + (size_t)row * NW;
        float acc[11][4];
        #pragma unroll
        for (int ol = 0; ol < 11; ++ol)
            #pragma unroll
            for (int i = 0; i < 4; ++i) acc[ol][i] = 0.f;
        float4 pre[4];
        {
            const float* s0 = in2_row + (size_t)(2 * q) * HW;
            const float* s1 = in2_row + (size_t)(2 * (q + 4)) * HW;
            pre[0] = ((const float4*)s0)[col4];
            pre[1] = ((const float4*)(s0 + HW))[col4];
            pre[2] = ((const float4*)s1)[col4];
            pre[3] = ((const float4*)(s1 + HW))[col4];
        }
        #pragma unroll 1
        for (int cb = 0; cb < NCB; ++cb) {
            {
                unsigned* da = &in2w[q * IN2_C2 + 2 * col4 + 10];
                unsigned* db = &in2w[(q + 4) * IN2_C2 + 2 * col4 + 10];
                *(uint2*)&da[0] = make_uint2(pk2(pre[0].x, pre[1].x), pk2(pre[0].z, pre[1].z));
                *(uint2*)&da[IN2_P] = make_uint2(pk2(pre[0].y, pre[1].y), pk2(pre[0].w, pre[1].w));
                *(uint2*)&db[0] = make_uint2(pk2(pre[2].x, pre[3].x), pk2(pre[2].z, pre[3].z));
                *(uint2*)&db[IN2_P] = make_uint2(pk2(pre[2].y, pre[3].y), pk2(pre[2].w, pre[3].w));
            }
            if (cb + 1 < NCB) {
                const float* srcn = in2_row + (size_t)((cb + 1) * 16) * HW;
                const float* s0 = srcn + (size_t)(2 * q) * HW;
                const float* s1 = srcn + (size_t)(2 * (q + 4)) * HW;
                pre[0] = ((const float4*)s0)[col4];
                pre[1] = ((const float4*)(s0 + HW))[col4];
                pre[2] = ((const float4*)s1)[col4];
                pre[3] = ((const float4*)(s1 + HW))[col4];
            }
            uint4 avv[4];
            uint2 wn[4][7];
            {
                const unsigned* base1 = &in1_s[(cb * 8 + chalf) * IN1_C2 + p * IN1_P + 4 * tw];
                const unsigned* base2 = &in2w[chalf * IN2_C2 + p * IN2_P + 4 * tw + 10 * oh];
                #pragma unroll
                for (int u = 0; u < 4; ++u) {
                    avv[u] = *(const uint4*)(base1 + (size_t)(2 * u) * IN1_C2);
                    #pragma unroll
                    for (int jj = 0; jj < 7; ++jj)
                        wn[u][jj] = *(const uint2*)(base2 + (size_t)(2 * u) * IN2_C2 + 2 * jj);
                }
            }
            #pragma unroll
            for (int u = 0; u < 4; ++u) {
                const half2v a0 = uph(avv[u].x), a1 = uph(avv[u].y);
                const half2v a2 = uph(avv[u].z), a3 = uph(avv[u].w);
                #pragma unroll
                for (int ol = 0; ol < 11; ++ol) {
                    acc[ol][0] = fdot2f(a0, WW(u, ol + 0), acc[ol][0]);
                    acc[ol][1] = fdot2f(a1, WW(u, ol + 1), acc[ol][1]);
                    acc[ol][2] = fdot2f(a2, WW(u, ol + 2), acc[ol][2]);
                    acc[ol][3] = fdot2f(a3, WW(u, ol + 3), acc[ol][3]);
                }
            }
        }
        #pragma unroll
        for (int ol = 0; ol < 11; ++ol)
            #pragma unroll
            for (int i = 0; i < 4; ++i) {
                float v = acc[ol][i];
                v += __shfl_xor(v, 32);
                acc[ol][i] = v;
            }
        if (chalf == 0) {
            #pragma unroll
            for (int ol = 0; ol < 11; ++ol) {
                if (oh == 1 && ol == 0) continue;
                const int og = 10 * oh + ol;
                #pragma unroll
                for (int i = 0; i < 4; ++i)
                    orow[(size_t)og * HW + (p + 8 * tw + 2 * i)] = acc[ol][i];
            }
        }
    }
}

// ---------------- host ----------------
extern "C" void kernel_launch(void* const* d_in, const int* in_sizes, int n_in,
                              void* d_out, int out_size, void* d_ws, size_t ws_size,
                              hipStream_t stream) {
    const float* in1 = (const float*)d_in[0];
    const float* in2 = (const float*)d_in[1];
    float* out = (float*)d_out;

    const size_t per_b = 1572864;  // 48*2*32*256*2 bytes
    int bc = 0;
    const int cands[5] = {16, 8, 4, 2, 1};
    for (int i = 0; i < 5; ++i) {
        if ((size_t)cands[i] * 2 * per_b <= ws_size) { bc = cands[i]; break; }
    }
    if (bc == 0) {
        corr_kernel<<<dim3(NB * NH), dim3(256), 0, stream>>>(in1, in2, out);
        return;
    }
    unsigned* t1 = (unsigned*)d_ws;
    unsigned* t2 = t1 + (size_t)bc * NH * 2 * 4096;
    const int nwg48 = bc * NH;
    for (int b0 = 0; b0 < NB; b0 += bc) {
        transpose_pack<<<dim3(2 * nwg48), dim3(256), 0, stream>>>(in1, in2, t1, t2, b0, nwg48);
        corr_mfma<<<dim3(nwg48 * 2), dim3(256), 0, stream>>>(t1, t2, out, b0, nwg48);
    }
}

// Round 13
// 92.063 us; speedup vs baseline: 1.0131x; 1.0131x over previous
//
#include <hip/hip_runtime.h>

// FlowNetC correlation, B=16 C=256 H=48 W=64, 21x21 displacements (stride 2, +/-20).
// out[b, i*21+j, h, w] = sum_c in1[b,c,h,w] * in2[b,c,h+2i-20,w+2j-20]  (zero OOB)
//
// v13 = v11 (full-oy blocks, 3/CU, DMA-staged B) + per-wave half-plane pipeline.
// Insight: wave (par,nt) stages exactly the 16 B-rows it alone reads -> the
// plane needs NO cross-wave barriers and per-wave counted vmcnt is exact.
// LDS re-keyed k-major per wave: [c 16][r 16] x16B per 4KB sub-buffer; one
// glds16 gathers a chunk-quad across all 16 rows (per-lane global addresses);
// k-halves (c 0..15 / 16..31) = disjoint sub-buffers; reads are conflict-free
// by construction (consecutive lanes -> consecutive rows -> 2-way max), so the
// old XOR swizzle + its 3.45M conflicts are gone.
// Per oy: {vmcnt(4): current half ready, newest 4 (prefetch) stay in flight ->
// 8 ds_read + 8 MFMA -> issue next oy's same-half 4x glds16 into the freed
// sub-buffer} x2, then scat -> lgkmcnt(0)+s_barrier -> copyout (slab dbuf).
// v12's regression (oy-chunking: +25MB A refetch, 2/CU occupancy) reverted.

#define NB 16
#define NC 256
#define NH 48
#define NW 64
#define HW (NH * NW)
#define CHW (NC * NH * NW)
#define ND 21
#define NDISP (ND * ND)

typedef __fp16 half2v __attribute__((ext_vector_type(2)));
typedef _Float16 f16x8 __attribute__((ext_vector_type(8)));
typedef float f32x16 __attribute__((ext_vector_type(16)));

__device__ __forceinline__ unsigned pk2(float lo, float hi) {
    half2v h = __builtin_amdgcn_cvt_pkrtz(lo, hi);
    return __builtin_bit_cast(unsigned, h);
}
__device__ __forceinline__ half2v uph(unsigned u) {
    return __builtin_bit_cast(half2v, u);
}

__device__ __forceinline__ void glds16(unsigned* l, const unsigned* g) {
    __builtin_amdgcn_global_load_lds(
        (const __attribute__((address_space(1))) unsigned*)g,
        (__attribute__((address_space(3))) unsigned*)l, 16, 0, 0);
}

// ---------------- Kernel T: transpose + pack (LDS-staged) ----------------
// src [b][c 256][h][w 64] f32 -> dst [(b_local*48+h)*2+par][w' 32][c2 128] u32
__global__ __launch_bounds__(256, 4)
void transpose_pack(const float* __restrict__ in1,
                    const float* __restrict__ in2,
                    unsigned* __restrict__ t1,
                    unsigned* __restrict__ t2,
                    int b_base, int nwg48) {
    __shared__ unsigned xs[64 * 129];        // [w 64][c2 128 +1 pad] -> conflict-free
    const int bx = blockIdx.x;
    const int which = (bx >= nwg48) ? 1 : 0;
    const int r = bx - which * nwg48;
    const int b_local = r / NH;
    const int h = r % NH;
    const float* src = (which ? in2 : in1) + (size_t)(b_base + b_local) * CHW + (size_t)h * NW;
    unsigned* dst = (which ? t2 : t1) + (size_t)((b_local * NH + h) * 2) * 4096;

    const int t = threadIdx.x;
    const int w = t & 63;
    const int c2b = t >> 6;                  // 0..3

    #pragma unroll 8
    for (int it = 0; it < 32; ++it) {
        const int c2 = c2b * 32 + it;
        const float lo = src[(size_t)(2 * c2) * HW + w];
        const float hi = src[(size_t)(2 * c2 + 1) * HW + w];
        xs[w * 129 + c2] = pk2(lo, hi);
    }
    __syncthreads();
    #pragma unroll 8
    for (int it = 0; it < 32; ++it) {
        const int k = t + 256 * it;          // 0..8191
        const int c2 = k & 127;
        const int wp = k >> 7;               // par = wp>>5, w' = wp&31
        dst[(size_t)(wp >> 5) * 4096 + (size_t)(wp & 31) * 128 + c2] =
            xs[(2 * (wp & 31) + (wp >> 5)) * 129 + c2];
    }
}

// ---------------- Kernel 2: banded-Gram MFMA, per-wave pipelined DMA ----------------
__global__ __launch_bounds__(256, 3)
void corr_mfma(const unsigned* __restrict__ in1T, const unsigned* __restrict__ in2T,
               float* __restrict__ out, int b_base, int nbh) {
    // per-wave B storage: [wave 4][half 2][c_local 16][r 16] x 16B  (32KB)
    __shared__ __align__(16) unsigned bpl[4][2][1024];
    __shared__ float slab[2][1428];          // dbuf [par 2][j 21][34] (11.4KB)

    const int t = threadIdx.x;
    const int lane = t & 63;
    const int wid = t >> 6;
    const int par = wid >> 1;
    const int nt = wid & 1;
    const int ln31 = lane & 31;
    const int kh = lane >> 5;

    const int bx = blockIdx.x;
    const int cpx = nbh >> 3;               // nbh = bc*48, divisible by 8
    const int L = (bx & 7) * cpx + (bx >> 3);
    const int b_local = L / NH;
    const int h = L % NH;
    const int b = b_base + b_local;

    float* out_b = out + (size_t)b * NDISP * HW + (size_t)h * NW;

    // B-lane geometry: w2' = nt*32 - 16 + ln31, zero OOB (masked at consume)
    const int w2p = nt * 32 - 16 + ln31;
    const bool bval = ((unsigned)w2p < 32u);
    const int r0 = bval ? (w2p - 16 * nt) : 0;   // local row within own half-plane

    const int lo = (h >= 20) ? 0 : ((21 - h) >> 1);
    const int hi = min(20, (67 - h) >> 1);

    // zero slabs for OOB oy rows
    #pragma unroll 1
    for (int oy = 0; oy < ND; ++oy) {
        if (oy >= lo && oy <= hi) continue;
        #pragma unroll
        for (int s_ = 0; s_ < 6; ++s_) {
            int k_ = t + 256 * s_;
            if (k_ < ND * NW)
                out_b[(size_t)(oy * ND + (k_ >> 6)) * HW + (k_ & 63)] = 0.f;
        }
    }

    // ---- A-frags to registers (once per block) ----
    const unsigned* pa = in1T +
        ((size_t)((b_local * NH + h) * 2 + par)) * 4096 + (size_t)ln31 * 128 + kh * 4;
    uint4 av[16];
    #pragma unroll
    for (int kk = 0; kk < 16; ++kk) av[kk] = *(const uint4*)(pa + 8 * kk);

    const unsigned* gplanes = in2T + ((size_t)(b_local * NH) * 2) * 4096;
    unsigned* wreg = &bpl[wid][0][0];
    // per-lane source base for staging: row = 16nt + (lane&15), chunk cq = lane>>4
    const int stg_off = (16 * nt + (lane & 15)) * 128 + ((lane >> 4) << 2);

#define STAGE(oy_, hf_)                                                       \
    do {                                                                      \
        const unsigned* gp = gplanes +                                        \
            ((size_t)((h + 2 * (oy_) - 20) * 2 + par)) * 4096 +               \
            stg_off + (hf_) * 64;  /* c += 16 -> words += 64 */               \
        unsigned* lp = wreg + (hf_) * 1024;                                   \
        _Pragma("unroll") for (int s_ = 0; s_ < 4; ++s_)                      \
            glds16(lp + s_ * 256, gp + 16 * s_);                              \
    } while (0)

#define CHALF(hf_)                                                            \
    do {                                                                      \
        const unsigned* lsub = wreg + (hf_) * 1024;                           \
        _Pragma("unroll") for (int k2 = 0; k2 < 8; ++k2) {                    \
            const uint4 qv =                                                  \
                *(const uint4*)(lsub + (((2 * k2 + kh) << 4) + r0) * 4);      \
            uint4 qq;                                                         \
            qq.x = bval ? qv.x : 0u;                                          \
            qq.y = bval ? qv.y : 0u;                                          \
            qq.z = bval ? qv.z : 0u;                                          \
            qq.w = bval ? qv.w : 0u;                                          \
            if (k2 & 1)                                                       \
                accB = __builtin_amdgcn_mfma_f32_32x32x16_f16(                \
                    __builtin_bit_cast(f16x8, av[8 * (hf_) + k2]),            \
                    __builtin_bit_cast(f16x8, qq), accB, 0, 0, 0);            \
            else                                                              \
                accA = __builtin_amdgcn_mfma_f32_32x32x16_f16(                \
                    __builtin_bit_cast(f16x8, av[8 * (hf_) + k2]),            \
                    __builtin_bit_cast(f16x8, qq), accA, 0, 0, 0);            \
        }                                                                     \
    } while (0)

#define SCAT(sb_, acc_)                                                       \
    do {                                                                      \
        _Pragma("unroll") for (int r_ = 0; r_ < 16; ++r_) {                   \
            const int m_ = (r_ & 3) + 8 * (r_ >> 2) + 4 * kh;                 \
            const int j_ = 32 * nt + ln31 - m_ - 6;                           \
            if ((unsigned)j_ < (unsigned)ND)                                  \
                (sb_)[par * 714 + j_ * 34 + m_] = acc_[r_];                   \
        }                                                                     \
    } while (0)

#define COPYOUT(oy_, sb_)                                                     \
    do {                                                                      \
        _Pragma("unroll") for (int s_ = 0; s_ < 6; ++s_) {                    \
            int k_ = t + 256 * s_;                                            \
            if (k_ < ND * NW) {                                               \
                int j_ = k_ >> 6, w_ = k_ & 63;                               \
                out_b[(size_t)((oy_)*ND + j_) * HW + w_] =                    \
                    (sb_)[(w_ & 1) * 714 + j_ * 34 + (w_ >> 1)];              \
            }                                                                 \
        }                                                                     \
    } while (0)

    // prologue: stage both halves of oy=lo (8 glds in flight)
    STAGE(lo, 0);
    STAGE(lo, 1);

    int buf = 0;
    #pragma unroll 1
    for (int oy = lo; oy <= hi; ++oy, buf ^= 1) {
        f32x16 accA, accB;
        #pragma unroll
        for (int i = 0; i < 16; ++i) { accA[i] = 0.f; accB[i] = 0.f; }

        // ---- half 0: wait own 4 loads (newest 4 = other half stays in flight)
        asm volatile("s_waitcnt vmcnt(4)" ::: "memory");
        __builtin_amdgcn_sched_barrier(0);
        __builtin_amdgcn_s_setprio(1);
        CHALF(0);
        __builtin_amdgcn_s_setprio(0);
        if (oy + 1 <= hi) STAGE(oy + 1, 0);   // refill freed sub-buffer

        // ---- half 1
        if (oy + 1 <= hi)
            asm volatile("s_waitcnt vmcnt(4)" ::: "memory");
        else
            asm volatile("s_waitcnt vmcnt(0)" ::: "memory");
        __builtin_amdgcn_sched_barrier(0);
        __builtin_amdgcn_s_setprio(1);
        CHALF(1);
        __builtin_amdgcn_s_setprio(0);
        if (oy + 1 <= hi) STAGE(oy + 1, 1);

        #pragma unroll
        for (int i = 0; i < 16; ++i) accA[i] += accB[i];

        float* sb = &slab[buf][0];
        SCAT(sb, accA);
        asm volatile("s_waitcnt lgkmcnt(0)" ::: "memory");
        __builtin_amdgcn_s_barrier();        // raw: DMA loads stay in flight
        COPYOUT(oy, sb);
    }
#undef STAGE
#undef CHALF
#undef SCAT
#undef COPYOUT
}

// ---------------- Fallback: v3 dot2 kernel ----------------
#define NCB 16
#define IN1_P 36
#define IN1_C2 (2 * IN1_P)
#define IN1_WORDS (128 * IN1_C2)
#define IN2_P 52
#define IN2_C2 (2 * IN2_P)
#define IN2_WAVE (8 * IN2_C2)
#define LDS_WORDS (IN1_WORDS + 4 * IN2_WAVE)

#if defined(__has_builtin)
#if __has_builtin(__builtin_amdgcn_fdot2)
#define HAVE_FDOT2 1
#endif
#endif
__device__ __forceinline__ float fdot2f(half2v a, half2v b, float c) {
#ifdef HAVE_FDOT2
    return __builtin_amdgcn_fdot2(a, b, c, false);
#else
    return c + (float)a.x * (float)b.x + (float)a.y * (float)b.y;
#endif
}
#define WW(u, m) uph(((m) & 1) ? wn[u][(m) >> 1].y : wn[u][(m) >> 1].x)

__global__ __launch_bounds__(256, 3)
void corr_kernel(const float* __restrict__ in1, const float* __restrict__ in2,
                 float* __restrict__ out) {
    __shared__ __align__(16) unsigned lds[LDS_WORDS];
    unsigned* in1_s = lds;
    const int t = threadIdx.x;
    const int lane = t & 63;
    const int wid = t >> 6;
    const int tw = lane & 7;
    const int oh = (lane >> 3) & 1;
    const int p = (lane >> 4) & 1;
    const int chalf = (lane >> 5) & 1;
    unsigned* in2w = lds + IN1_WORDS + wid * IN2_WAVE;
    const int bx = blockIdx.x;
    const int L = (bx & 7) * 96 + (bx >> 3);
    const int b = L / NH;
    const int h = L % NH;
    const float* in1_row = in1 + (size_t)b * CHW + (size_t)h * NW;
    for (int i = lane; i < IN2_WAVE; i += 64) in2w[i] = 0u;
    #pragma unroll 1
    for (int j = 0; j < 8; ++j) {
        const int task = t + 256 * j;
        const int c2 = task >> 4;
        const int c4 = task & 15;
        const float4 u0 = ((const float4*)(in1_row + (size_t)(2 * c2) * HW))[c4];
        const float4 u1 = ((const float4*)(in1_row + (size_t)(2 * c2 + 1) * HW))[c4];
        unsigned* d0 = &in1_s[c2 * IN1_C2 + 2 * c4];
        *(uint2*)&d0[0] = make_uint2(pk2(u0.x, u1.x), pk2(u0.z, u1.z));
        *(uint2*)&d0[IN1_P] = make_uint2(pk2(u0.y, u1.y), pk2(u0.w, u1.w));
    }
    __syncthreads();
    const int q = lane >> 4;
    const int col4 = lane & 15;
    const int lo = (h >= 20) ? 0 : ((21 - h) >> 1);
    const int hi = min(20, (67 - h) >> 1);
    const int nv = hi - lo + 1;
    const int rot = (wid + h) & 3;
    #pragma unroll 1
    for (int oy = rot; oy < ND; oy += 4) {
        if (oy >= lo && oy <= hi) continue;
        float* orow = out + ((size_t)(b * NDISP + oy * ND) * NH + h) * NW;
        #pragma unroll
        for (int o = 0; o < ND; ++o) orow[(size_t)o * HW + lane] = 0.f;
    }
    #pragma unroll 1
    for (int k = rot; k < nv; k += 4) {
        const int oyi = lo + k;
        const int row = h + 2 * oyi - 20;
        float* orow = out + ((size_t)(b * NDISP + oyi * ND) * NH + h) * NW;
        const float* in2_row = in2 + (size_t)b * CHW + (size_t)row * NW;
        float acc[11][4];
        #pragma unroll
        for (int ol = 0; ol < 11; ++ol)
            #pragma unroll
            for (int i = 0; i < 4; ++i) acc[ol][i] = 0.f;
        float4 pre[4];
        {
            const float* s0 = in2_row + (size_t)(2 * q) * HW;
            const float* s1 = in2_row + (size_t)(2 * (q + 4)) * HW;
            pre[0] = ((const float4*)s0)[col4];
            pre[1] = ((const float4*)(s0 + HW))[col4];
            pre[2] = ((const float4*)s1)[col4];
            pre[3] = ((const float4*)(s1 + HW))[col4];
        }
        #pragma unroll 1
        for (int cb = 0; cb < NCB; ++cb) {
            {
                unsigned* da = &in2w[q * IN2_C2 + 2 * col4 + 10];
                unsigned* db = &in2w[(q + 4) * IN2_C2 + 2 * col4 + 10];
                *(uint2*)&da[0] = make_uint2(pk2(pre[0].x, pre[1].x), pk2(pre[0].z, pre[1].z));
                *(uint2*)&da[IN2_P] = make_uint2(pk2(pre[0].y, pre[1].y), pk2(pre[0].w, pre[1].w));
                *(uint2*)&db[0] = make_uint2(pk2(pre[2].x, pre[3].x), pk2(pre[2].z, pre[3].z));
                *(uint2*)&db[IN2_P] = make_uint2(pk2(pre[2].y, pre[3].y), pk2(pre[2].w, pre[3].w));
            }
            if (cb + 1 < NCB) {
                const float* srcn = in2_row + (size_t)((cb + 1) * 16) * HW;
                const float* s0 = srcn + (size_t)(2 * q) * HW;
                const float* s1 = srcn + (size_t)(2 * (q + 4)) * HW;
                pre[0] = ((const float4*)s0)[col4];
                pre[1] = ((const float4*)(s0 + HW))[col4];
                pre[2] = ((const float4*)s1)[col4];
                pre[3] = ((const float4*)(s1 + HW))[col4];
            }
            uint4 avv[4];
            uint2 wn[4][7];
            {
                const unsigned* base1 = &in1_s[(cb * 8 + chalf) * IN1_C2 + p * IN1_P + 4 * tw];
                const unsigned* base2 = &in2w[chalf * IN2_C2 + p * IN2_P + 4 * tw + 10 * oh];
                #pragma unroll
                for (int u = 0; u < 4; ++u) {
                    avv[u] = *(const uint4*)(base1 + (size_t)(2 * u) * IN1_C2);
                    #pragma unroll
                    for (int jj = 0; jj < 7; ++jj)
                        wn[u][jj] = *(const uint2*)(base2 + (size_t)(2 * u) * IN2_C2 + 2 * jj);
                }
            }
            #pragma unroll
            for (int u = 0; u < 4; ++u) {
                const half2v a0 = uph(avv[u].x), a1 = uph(avv[u].y);
                const half2v a2 = uph(avv[u].z), a3 = uph(avv[u].w);
                #pragma unroll
                for (int ol = 0; ol < 11; ++ol) {
                    acc[ol][0] = fdot2f(a0, WW(u, ol + 0), acc[ol][0]);
                    acc[ol][1] = fdot2f(a1, WW(u, ol + 1), acc[ol][1]);
                    acc[ol][2] = fdot2f(a2, WW(u, ol + 2), acc[ol][2]);
                    acc[ol][3] = fdot2f(a3, WW(u, ol + 3), acc[ol][3]);
                }
            }
        }
        #pragma unroll
        for (int ol = 0; ol < 11; ++ol)
            #pragma unroll
            for (int i = 0; i < 4; ++i) {
                float v = acc[ol][i];
                v += __shfl_xor(v, 32);
                acc[ol][i] = v;
            }
        if (chalf == 0) {
            #pragma unroll
            for (int ol = 0; ol < 11; ++ol) {
                if (oh == 1 && ol == 0) continue;
                const int og = 10 * oh + ol;
                #pragma unroll
                for (int i = 0; i < 4; ++i)
                    orow[(size_t)og * HW + (p + 8 * tw + 2 * i)] = acc[ol][i];
            }
        }
    }
}

// ---------------- host ----------------
extern "C" void kernel_launch(void* const* d_in, const int* in_sizes, int n_in,
                              void* d_out, int out_size, void* d_ws, size_t ws_size,
                              hipStream_t stream) {
    const float* in1 = (const float*)d_in[0];
    const float* in2 = (const float*)d_in[1];
    float* out = (float*)d_out;

    const size_t per_b = 1572864;  // 48*2*32*256*2 bytes
    int bc = 0;
    const int cands[5] = {16, 8, 4, 2, 1};
    for (int i = 0; i < 5; ++i) {
        if ((size_t)cands[i] * 2 * per_b <= ws_size) { bc = cands[i]; break; }
    }
    if (bc == 0) {
        corr_kernel<<<dim3(NB * NH), dim3(256), 0, stream>>>(in1, in2, out);
        return;
    }
    unsigned* t1 = (unsigned*)d_ws;
    unsigned* t2 = t1 + (size_t)bc * NH * 2 * 4096;
    const int nwg48 = bc * NH;
    for (int b0 = 0; b0 < NB; b0 += bc) {
        transpose_pack<<<dim3(2 * nwg48), dim3(256), 0, stream>>>(in1, in2, t1, t2, b0, nwg48);
        corr_mfma<<<dim3(nwg48), dim3(256), 0, stream>>>(t1, t2, out, b0, nwg48);
    }
}